// Round 16
// baseline (170.073 us; speedup 1.0000x reference)
//
#include <hip/hip_runtime.h>
#include <hip/hip_bf16.h>

#define DD 256
#define TTT 512
#define BB 16
#define KK 3
#define MAXO 4096
#define LN_EPS 1e-5f
#define TPAD 514   // 512 rows + 1 zero pad row each side (per batch)
#define NKT 24     // K-steps: 768 / 32

typedef __attribute__((ext_vector_type(8))) short short8;   // bf16x8
typedef __attribute__((ext_vector_type(4))) float f32x4;

static __device__ inline short bf16r(float v) {
    __hip_bfloat16 h = __float2bfloat16(v);   // RNE rounding
    return reinterpret_cast<short&>(h);
}

// ---- fused prep: blocks [0,16) cumsum+scatter | [16,112) weight pack |
//                  [112,626) x->bf16 pad (short8-vectorized).  blockDim = 512.
__global__ __launch_bounds__(512) void k_prep_all(
    const float* __restrict__ x, const int* __restrict__ mf,
    const float* __restrict__ w, short* __restrict__ wpk,
    short* __restrict__ xb, short* __restrict__ h1b,
    int* __restrict__ cum, int* __restrict__ idxb, float* __restrict__ dout) {
    __shared__ int s[TTT];
    int blk = blockIdx.x;
    if (blk < 16) {
        // ---- cumsum per batch; lengths (as float) + loss zero + idx scatter
        int b = blk, t = threadIdx.x;
        s[t] = mf[b * TTT + t];
        __syncthreads();
        for (int off = 1; off < TTT; off <<= 1) {
            int v = (t >= off) ? s[t - off] : 0;
            __syncthreads();
            s[t] += v;
            __syncthreads();
        }
        cum[b * TTT + t] = s[t];
        int hi = s[t];
        int lo = (t == 0) ? 0 : s[t - 1];
        for (int p = lo; p < hi; ++p) idxb[b * MAXO + p] = t;
        if (t == TTT - 1) dout[(size_t)BB * MAXO * DD + b] = (float)s[t];
        if (b == 0 && t == 0) dout[(size_t)BB * MAXO * DD + BB] = 0.f;
    } else if (blk < 112) {
        // ---- pack weights into MFMA B-fragment order (96*512 = 49152 exact)
        int tid = (blk - 16) * 512 + threadIdx.x;
        int lane = tid & 63;
        int rest = tid >> 6;
        int nf = rest & 15; rest >>= 4;
        int kt = rest % NKT;
        int l  = rest / NKT;
        int n     = nf * 16 + (lane & 15);
        int kbase = kt * 32 + (lane >> 4) * 8;
        short8 v;
#pragma unroll
        for (int j = 0; j < 8; ++j) {
            int k   = kbase + j;
            int kap = k >> 8;       // tap
            int i   = k & 255;      // input channel
            v[j] = bf16r(w[(((l * DD) + n) * DD + i) * KK + kap]);
        }
        *reinterpret_cast<short8*>(wpk + (size_t)tid * 8) = v;
    } else {
        // ---- x -> padded bf16, 8 channels/thread: 514*512 = 263168 = BB*TPAD*32
        int t8 = (blk - 112) * 512 + threadIdx.x;
        int rowg = t8 >> 5;                 // [0, BB*TPAD)
        int c0   = (t8 & 31) << 3;
        int r = rowg % TPAD;
        int b = rowg / TPAD;
        size_t o8 = (size_t)t8 * 8;
        if (r == 0 || r == TPAD - 1) {
            short8 z = {0,0,0,0,0,0,0,0};
            *reinterpret_cast<short8*>(xb + o8)  = z;
            *reinterpret_cast<short8*>(h1b + o8) = z;
        } else {
            const float* src = x + ((size_t)b * TTT + (r - 1)) * DD + c0;
            float4 fA = *reinterpret_cast<const float4*>(src);
            float4 fB = *reinterpret_cast<const float4*>(src + 4);
            short8 v;
            v[0] = bf16r(fA.x); v[1] = bf16r(fA.y); v[2] = bf16r(fA.z); v[3] = bf16r(fA.w);
            v[4] = bf16r(fB.x); v[5] = bf16r(fB.y); v[6] = bf16r(fB.z); v[7] = bf16r(fB.w);
            *reinterpret_cast<short8*>(xb + o8) = v;
        }
    }
}

// ---- conv core (MFMA) + ReLU + LN (+ linear/MSE loss), callable body -------
template <bool DO_LOSS>
static __device__ inline void conv_body(
    int bt, int tid,
    const short* __restrict__ ain, short* __restrict__ aout,
    const short8* __restrict__ bp, const float* __restrict__ cb,
    const float* __restrict__ g, const float* __restrict__ bvec,
    const float* __restrict__ lw, const float* __restrict__ lb,
    const int* __restrict__ mf, float* __restrict__ loss,
    float (*yt)[260]) {
    int b  = bt >> 5;
    int t0 = (bt & 31) << 4;
    int lane = tid & 63, wv = tid >> 6;
    int mrow = lane & 15;            // A row / C col index
    int kg   = lane >> 4;            // k-group

    const short* Ab = ain + ((size_t)b * TPAD + t0 + mrow) * DD + kg * 8;
    f32x4 acc0 = {0.f,0.f,0.f,0.f}, acc1 = acc0, acc2 = acc0, acc3 = acc0;
    const short8* bw = bp + (size_t)wv * 4 * 64 + lane;

    for (int kt = 0; kt < NKT; ++kt) {
        short8 a  = *reinterpret_cast<const short8*>(Ab + kt * 32);
        short8 b0 = bw[0];
        short8 b1 = bw[64];
        short8 b2 = bw[128];
        short8 b3 = bw[192];
        acc0 = __builtin_amdgcn_mfma_f32_16x16x32_bf16(a, b0, acc0, 0, 0, 0);
        acc1 = __builtin_amdgcn_mfma_f32_16x16x32_bf16(a, b1, acc1, 0, 0, 0);
        acc2 = __builtin_amdgcn_mfma_f32_16x16x32_bf16(a, b2, acc2, 0, 0, 0);
        acc3 = __builtin_amdgcn_mfma_f32_16x16x32_bf16(a, b3, acc3, 0, 0, 0);
        bw += 16 * 64;
    }

    // bias + ReLU -> LDS tile. C layout: col=lane&15, row=kg*4+reg (m89-verified).
#define EPI(F, ACC) { int c = ((wv * 4 + F) << 4) + mrow; float bias = cb[c];   \
        yt[kg * 4 + 0][c] = fmaxf(ACC[0] + bias, 0.f);                          \
        yt[kg * 4 + 1][c] = fmaxf(ACC[1] + bias, 0.f);                          \
        yt[kg * 4 + 2][c] = fmaxf(ACC[2] + bias, 0.f);                          \
        yt[kg * 4 + 3][c] = fmaxf(ACC[3] + bias, 0.f); }
    EPI(0, acc0) EPI(1, acc1) EPI(2, acc2) EPI(3, acc3)
#undef EPI
    __syncthreads();

    float lsum = 0.f;
    int c0 = lane << 1;
#pragma unroll
    for (int q = 0; q < 4; ++q) {
        int r = wv * 4 + q;
        float2 vA = *reinterpret_cast<float2*>(&yt[r][c0]);
        float2 vB = *reinterpret_cast<float2*>(&yt[r][c0 + 128]);
        float s  = vA.x + vA.y + vB.x + vB.y;
        float s2 = vA.x*vA.x + vA.y*vA.y + vB.x*vB.x + vB.y*vB.y;
#pragma unroll
        for (int off = 1; off < 64; off <<= 1) {
            s  += __shfl_xor(s, off);
            s2 += __shfl_xor(s2, off);
        }
        float mean = s * (1.f / DD);
        float var  = s2 * (1.f / DD) - mean * mean;
        float rs   = rsqrtf(var + LN_EPS);
        float2 gA = *reinterpret_cast<const float2*>(&g[c0]);
        float2 gB = *reinterpret_cast<const float2*>(&g[c0 + 128]);
        float2 bA = *reinterpret_cast<const float2*>(&bvec[c0]);
        float2 bB = *reinterpret_cast<const float2*>(&bvec[c0 + 128]);
        float oAx = (vA.x - mean) * rs * gA.x + bA.x;
        float oAy = (vA.y - mean) * rs * gA.y + bA.y;
        float oBx = (vB.x - mean) * rs * gB.x + bB.x;
        float oBy = (vB.y - mean) * rs * gB.y + bB.y;
        if constexpr (!DO_LOSS) {
            size_t rowb = ((size_t)b * TPAD + t0 + r + 1) * DD;
            short2 sA, sB;
            sA.x = bf16r(oAx); sA.y = bf16r(oAy);
            sB.x = bf16r(oBx); sB.y = bf16r(oBy);
            *reinterpret_cast<short2*>(&aout[rowb + c0])       = sA;
            *reinterpret_cast<short2*>(&aout[rowb + c0 + 128]) = sB;
        } else {
            float2 lA = *reinterpret_cast<const float2*>(&lw[c0]);
            float2 lB = *reinterpret_cast<const float2*>(&lw[c0 + 128]);
            float p = oAx * lA.x + oAy * lA.y + oBx * lB.x + oBy * lB.y;
#pragma unroll
            for (int off = 1; off < 64; off <<= 1) p += __shfl_xor(p, off);
            if (lane == 0) {
                float dv = p + lb[0];
                float er = dv - (float)mf[b * TTT + t0 + r];
                lsum += er * er;
            }
        }
    }
    if constexpr (DO_LOSS) {
        if (lane == 0) atomicAdd(loss, lsum * (1.f / (BB * TTT)));
    }
}

// ---- mid: blocks [0,2048) length regulator | [2048,2560) conv layer 1 ------
__global__ __launch_bounds__(256) void k_mid(
    const short* __restrict__ xb, short* __restrict__ h1b,
    const short8* __restrict__ bp, const float* __restrict__ cb,
    const float* __restrict__ g, const float* __restrict__ bvec,
    const float* __restrict__ x, const int* __restrict__ cum,
    const int* __restrict__ idxb, float* __restrict__ out) {
    __shared__ float yt[16][260];
    int blk = blockIdx.x;
    int tid = threadIdx.x;
    if (blk >= 2048) {
        conv_body<false>(blk - 2048, tid, xb, h1b, bp, cb, g, bvec,
                         nullptr, nullptr, nullptr, nullptr, yt);
    } else {
        int b   = blk >> 7;            // MAXO/32 = 128 tiles per batch
        int p0  = (blk & 127) << 5;
        int lane = tid & 63, wv = tid >> 6;
        int len = cum[b * TTT + TTT - 1];
        const float4* x4 = (const float4*)x;
        float4* o4 = (float4*)out;
#pragma unroll
        for (int r = 0; r < 8; ++r) {
            int p = p0 + (wv << 3) + r;
            size_t oidx = ((size_t)b * MAXO + p) * 64 + lane;
            if (p < len) {
                int idx = idxb[b * MAXO + p];      // wave-uniform broadcast
                o4[oidx] = x4[((size_t)b * TTT + idx) * 64 + lane];
            } else {
                o4[oidx] = make_float4(0.f, 0.f, 0.f, 0.f);
            }
        }
    }
}

// ---- final: conv layer 2 + linear + MSE loss -------------------------------
__global__ __launch_bounds__(256) void k_final(
    const short* __restrict__ h1b, const short8* __restrict__ bp,
    const float* __restrict__ cb, const float* __restrict__ g,
    const float* __restrict__ bvec, const float* __restrict__ lw,
    const float* __restrict__ lb, const int* __restrict__ mf,
    float* __restrict__ loss) {
    __shared__ float yt[16][260];
    conv_body<true>(blockIdx.x, threadIdx.x, h1b, nullptr, bp, cb, g, bvec,
                    lw, lb, mf, loss, yt);
}

extern "C" void kernel_launch(void* const* d_in, const int* in_sizes, int n_in,
                              void* d_out, int out_size, void* d_ws, size_t ws_size,
                              hipStream_t stream) {
    const float* x      = (const float*)d_in[0];
    const int*   mf     = (const int*)d_in[1];
    const float* conv_w = (const float*)d_in[4];
    const float* conv_b = (const float*)d_in[5];
    const float* ln_g   = (const float*)d_in[6];
    const float* ln_b   = (const float*)d_in[7];
    const float* lin_w  = (const float*)d_in[8];
    const float* lin_b  = (const float*)d_in[9];
    float* out = (float*)d_out;

    short* wpk = (short*)d_ws;                        // 786 KB
    short* xb  = wpk + (size_t)2 * NKT * 16 * 64 * 8; // 4.2 MB
    short* h1b = xb + (size_t)BB * TPAD * DD;         // 4.2 MB
    int*   cum  = (int*)(h1b + (size_t)BB * TPAD * DD);  // 32 KB
    int*   idxb = cum + BB * TTT;                        // 262 KB

    float* lossp = out + (size_t)BB * MAXO * DD + BB;

    k_prep_all<<<16 + 96 + 514, 512, 0, stream>>>(
        x, mf, conv_w, wpk, xb, h1b, cum, idxb, out);
    k_mid<<<2048 + 512, 256, 0, stream>>>(
        xb, h1b, (const short8*)wpk, conv_b, ln_g, ln_b,
        x, cum, idxb, out);
    k_final<<<512, 256, 0, stream>>>(
        h1b, (const short8*)wpk + (size_t)NKT * 16 * 64,
        conv_b + DD, ln_g + DD, ln_b + DD, lin_w, lin_b, mf, lossp);
}